// Round 3
// baseline (471.674 us; speedup 1.0000x reference)
//
#include <hip/hip_runtime.h>
#include <math.h>

#define NB 8
#define NP 4096
#define TOPK 10
#define KNB 9
#define QPB 64              // queries per block (one per lane)
#define NW 4                // waves per block = candidate quarters
#define LQ 1024             // candidates per quarter
#define SYNCI 128           // candidates between threshold syncs
#define MST 41              // merge row stride (4*10 + 1 pad)

#define FINF 3.0e38f
#define PI_F 3.14159274101257324f

__global__ __launch_bounds__(256, 2)
void repsurf_knn(const float* __restrict__ x,
                 const float* __restrict__ cw1,
                 const float* __restrict__ bg1, const float* __restrict__ bb1,
                 const float* __restrict__ bm1, const float* __restrict__ bv1,
                 const float* __restrict__ cw2, const float* __restrict__ cb2,
                 const float* __restrict__ bg2, const float* __restrict__ bb2,
                 const float* __restrict__ bm2, const float* __restrict__ bv2,
                 const float* __restrict__ cw3, const float* __restrict__ cb3,
                 float* __restrict__ out)
{
    __shared__ __align__(16) float4 tile[NP];   // 64 KB; overlaid by merge lists after scan
    __shared__ float thrLds[256];
    __shared__ __align__(16) float sW1[9 * 12];
    __shared__ __align__(16) float sW2[9 * 12];
    __shared__ __align__(16) float sW3[9 * 12];
    __shared__ float sSh1[9], sSh2[9], sSh3[9];

    const int t  = threadIdx.x;
    const int b  = blockIdx.x >> 6;      // 64 chunks per batch
    const int qc = blockIdx.x & 63;
    const float* xb = x + (size_t)b * 3 * NP;

    // ---- stage all 4096 candidates as AoS float4 (x,y,z,0) ----
#pragma unroll
    for (int r = 0; r < 4; ++r) {
        int c4 = r * 1024 + t * 4;
        float4 X = *(const float4*)(xb + c4);
        float4 Y = *(const float4*)(xb + NP + c4);
        float4 Z = *(const float4*)(xb + 2 * NP + c4);
        tile[c4 + 0] = make_float4(X.x, Y.x, Z.x, 0.f);
        tile[c4 + 1] = make_float4(X.y, Y.y, Z.y, 0.f);
        tile[c4 + 2] = make_float4(X.z, Y.z, Z.z, 0.f);
        tile[c4 + 3] = make_float4(X.w, Y.w, Z.w, 0.f);
    }
    // ---- fold BN into conv weights ----
    if (t < 108) {
        int o = t / 12, c = t % 12;
        float w1v = 0.f, w2v = 0.f, w3v = 0.f;
        if (c < 9) {
            float iv1 = bg1[o] * rsqrtf(bv1[o] + 1e-5f);
            float iv2 = bg2[o] * rsqrtf(bv2[o] + 1e-5f);
            w1v = cw1[o * 9 + c] * iv1;
            w2v = cw2[o * 9 + c] * iv2;
            w3v = cw3[o * 9 + c];
        }
        sW1[t] = w1v; sW2[t] = w2v; sW3[t] = w3v;
        if (t < 9) {
            float iv1 = bg1[t] * rsqrtf(bv1[t] + 1e-5f);
            float iv2 = bg2[t] * rsqrtf(bv2[t] + 1e-5f);
            sSh1[t] = bb1[t] - bm1[t] * iv1;
            sSh2[t] = cb2[t] * iv2 + bb2[t] - bm2[t] * iv2;
            sSh3[t] = cb3[t];
        }
    }
    __syncthreads();

    const int w  = t >> 6;               // wave = candidate quarter
    const int l  = t & 63;               // lane = query
    const int qi = qc * QPB + l;
    const float4 qv = tile[qi];
    const float qx = qv.x, qy = qv.y, qz = qv.z;

    float dk[TOPK];
    int   ik[TOPK];
#pragma unroll
    for (int j = 0; j < TOPK; ++j) { dk[j] = FINF; ik[j] = 0x7fffffff; }

#define INSERTE(DD, II) do { \
        float _d = (DD); int _i = (II); \
        if (_d < dk[TOPK - 1]) { \
            dk[TOPK - 1] = _d; ik[TOPK - 1] = _i; \
            _Pragma("unroll") \
            for (int jj = TOPK - 1; jj > 0; --jj) { \
                if (dk[jj] < dk[jj - 1]) { \
                    float td = dk[jj]; dk[jj] = dk[jj - 1]; dk[jj - 1] = td; \
                    int ti = ik[jj]; ik[jj] = ik[jj - 1]; ik[jj - 1] = ti; } \
            } \
        } } while (0)

#define CAND(P, IDX) do { \
        float dx = (P).x - qx, dy = (P).y - qy, dz = (P).z - qz; \
        float d = fmaf(dx, dx, fmaf(dy, dy, dz * dz)); \
        if (d <= thr) INSERTE(d, (IDX)); } while (0)

    // ---- scan this wave's quarter; shared pruning threshold across waves ----
    float thr = FINF;
    const int cbase = w * LQ;
    for (int sg = 0; sg < LQ / SYNCI; ++sg) {
        const int sb = cbase + sg * SYNCI;
#pragma unroll 4
        for (int u = 0; u < SYNCI / 4; ++u) {
            const int c0 = sb + u * 4;
            float4 P0 = tile[c0 + 0];
            float4 P1 = tile[c0 + 1];
            float4 P2 = tile[c0 + 2];
            float4 P3 = tile[c0 + 3];
            CAND(P0, c0 + 0);
            CAND(P1, c0 + 1);
            CAND(P2, c0 + 2);
            CAND(P3, c0 + 3);
        }
        // threshold sync: thr = min over the 4 waves of each lane's local 10th
        thrLds[t] = dk[TOPK - 1];
        __syncthreads();
        float t0 = thrLds[l], t1 = thrLds[64 + l];
        float t2 = thrLds[128 + l], t3 = thrLds[192 + l];
        thr = fminf(fminf(t0, t1), fminf(t2, t3));
        __syncthreads();
    }

    // ---- overlay merge lists onto the (now dead) tile ----
    float* md = (float*)tile;                 // [QPB][MST]
    int*   mi = (int*)((float*)tile + QPB * MST);
    const int mb = l * MST + w * TOPK;
#pragma unroll
    for (int j = 0; j < TOPK; ++j) {
        md[mb + j] = dk[j];
        mi[mb + j] = ik[j];
    }
    __syncthreads();

    // ---- phase 2: 4-way merge + geometry + MLP (wave 0, 64 lanes) ----
    if (t < QPB) {
        const int qb = t * MST;
        int ni[KNB];
        int p0 = 0, p1 = 0, p2 = 0, p3 = 0;
#pragma unroll
        for (int j = 0; j < TOPK; ++j) {
            float d0 = (p0 < TOPK) ? md[qb + p0]            : FINF;
            int   i0 = (p0 < TOPK) ? mi[qb + p0]            : 0x7fffffff;
            float d1 = (p1 < TOPK) ? md[qb + TOPK + p1]     : FINF;
            int   i1 = (p1 < TOPK) ? mi[qb + TOPK + p1]     : 0x7fffffff;
            float d2 = (p2 < TOPK) ? md[qb + 2 * TOPK + p2] : FINF;
            int   i2 = (p2 < TOPK) ? mi[qb + 2 * TOPK + p2] : 0x7fffffff;
            float d3 = (p3 < TOPK) ? md[qb + 3 * TOPK + p3] : FINF;
            int   i3 = (p3 < TOPK) ? mi[qb + 3 * TOPK + p3] : 0x7fffffff;
            bool w01 = (d0 < d1) || (d0 == d1 && i0 < i1);
            float dA = w01 ? d0 : d1; int iA = w01 ? i0 : i1; int sA = w01 ? 0 : 1;
            bool w23 = (d2 < d3) || (d2 == d3 && i2 < i3);
            float dB = w23 ? d2 : d3; int iB = w23 ? i2 : i3; int sB = w23 ? 2 : 3;
            bool wA = (dA < dB) || (dA == dB && iA < iB);
            int iw = wA ? iA : iB; int sw = wA ? sA : sB;
            if (j > 0) ni[j - 1] = iw;        // drop entry 0 == self (d = 0)
            p0 += (sw == 0); p1 += (sw == 1); p2 += (sw == 2); p3 += (sw == 3);
        }

        // gather relative neighbor coords (global; L1/L2-hot) + azimuth key
        float gx[KNB], gy[KNB], gz[KNB], kk[KNB];
#pragma unroll
        for (int j = 0; j < KNB; ++j) {
            int id = ni[j];
            gx[j] = xb[id] - qx;
            gy[j] = xb[NP + id] - qy;
            gz[j] = xb[2 * NP + id] - qz;
            kk[j] = atan2f(gy[j], gx[j]);
        }
        // stable bubble sort by azimuth
#pragma unroll
        for (int pass = 0; pass < KNB - 1; ++pass) {
#pragma unroll
            for (int j = 0; j < KNB - 1 - pass; ++j) {
                if (kk[j + 1] < kk[j]) {
                    float tv;
                    tv = kk[j]; kk[j] = kk[j + 1]; kk[j + 1] = tv;
                    tv = gx[j]; gx[j] = gx[j + 1]; gx[j + 1] = tv;
                    tv = gy[j]; gy[j] = gy[j + 1]; gy[j + 1] = tv;
                    tv = gz[j]; gz[j] = gz[j + 1]; gz[j + 1] = tv;
                }
            }
        }

        // umbrella normals
        float ux[KNB], uy[KNB], uz[KNB];
#pragma unroll
        for (int j = 0; j < KNB; ++j) {
            int j2 = (j + 1 == KNB) ? 0 : j + 1;
            float nx_ = gy[j] * gz[j2] - gz[j] * gy[j2];
            float ny_ = gz[j] * gx[j2] - gx[j] * gz[j2];
            float nz_ = gx[j] * gy[j2] - gy[j] * gx[j2];
            float ln = sqrtf(nx_ * nx_ + ny_ * ny_ + nz_ * nz_);
            float inv = 1.0f / fmaxf(ln, 1e-10f);
            ux[j] = nx_ * inv; uy[j] = ny_ * inv; uz[j] = nz_ * inv;
        }
        float sgn = (ux[0] > 0.0f) ? 1.0f : -1.0f;

        const float4* W1v = (const float4*)sW1;
        const float4* W2v = (const float4*)sW2;
        const float4* W3v = (const float4*)sW3;

#define DOT9(WV, O, V) ( \
        (WV)[(O)*3+0].x * (V)[0] + (WV)[(O)*3+0].y * (V)[1] + \
        (WV)[(O)*3+0].z * (V)[2] + (WV)[(O)*3+0].w * (V)[3] + \
        (WV)[(O)*3+1].x * (V)[4] + (WV)[(O)*3+1].y * (V)[5] + \
        (WV)[(O)*3+1].z * (V)[6] + (WV)[(O)*3+1].w * (V)[7] + \
        (WV)[(O)*3+2].x * (V)[8] )

        float acc[9];
#pragma unroll
        for (int o = 0; o < 9; ++o) acc[o] = 0.0f;

#pragma unroll
        for (int j = 0; j < KNB; ++j) {
            int j2 = (j + 1 == KNB) ? 0 : j + 1;
            float cx = (gx[j] + gx[j2]) * (1.0f / 3.0f);
            float cy = (gy[j] + gy[j2]) * (1.0f / 3.0f);
            float cz = (gz[j] + gz[j2]) * (1.0f / 3.0f);
            float rho = sqrtf(cx * cx + cy * cy + cz * cz);
            float rs  = fmaxf(rho, 1e-8f);
            float ct  = fminf(fmaxf(cz / rs, -1.0f), 1.0f);
            float th  = acosf(ct) / PI_F;
            float ph  = atan2f(cy, cx) / (2.0f * PI_F) + 0.5f;
            float f[9]  = {cx, cy, cz, rho, th, ph, ux[j] * sgn, uy[j] * sgn, uz[j] * sgn};
            float t1[9], t2[9];
#pragma unroll
            for (int o = 0; o < 9; ++o)
                t1[o] = fmaxf(DOT9(W1v, o, f) + sSh1[o], 0.0f);
#pragma unroll
            for (int o = 0; o < 9; ++o)
                t2[o] = fmaxf(DOT9(W2v, o, t1) + sSh2[o], 0.0f);
#pragma unroll
            for (int o = 0; o < 9; ++o)
                acc[o] += DOT9(W3v, o, t2);
        }

        float* ob = out + (size_t)b * 9 * NP;
#pragma unroll
        for (int o = 0; o < 9; ++o)
            ob[o * NP + qi] = acc[o] + 9.0f * sSh3[o];
    }
}

extern "C" void kernel_launch(void* const* d_in, const int* in_sizes, int n_in,
                              void* d_out, int out_size, void* d_ws, size_t ws_size,
                              hipStream_t stream) {
    const float* x   = (const float*)d_in[0];
    const float* cw1 = (const float*)d_in[1];
    const float* bg1 = (const float*)d_in[2];
    const float* bb1 = (const float*)d_in[3];
    const float* bm1 = (const float*)d_in[4];
    const float* bv1 = (const float*)d_in[5];
    const float* cw2 = (const float*)d_in[6];
    const float* cb2 = (const float*)d_in[7];
    const float* bg2 = (const float*)d_in[8];
    const float* bb2 = (const float*)d_in[9];
    const float* bm2 = (const float*)d_in[10];
    const float* bv2 = (const float*)d_in[11];
    const float* cw3 = (const float*)d_in[12];
    const float* cb3 = (const float*)d_in[13];
    float* out = (float*)d_out;

    hipLaunchKernelGGL(repsurf_knn, dim3(NB * (NP / QPB)), dim3(256), 0, stream,
                       x, cw1, bg1, bb1, bm1, bv1, cw2, cb2, bg2, bb2, bm2, bv2,
                       cw3, cb3, out);
}

// Round 4
// 349.430 us; speedup vs baseline: 1.3498x; 1.3498x over previous
//
#include <hip/hip_runtime.h>
#include <math.h>

#define NB 8
#define NP 4096
#define TOPK 10
#define KNB 9
#define QPB 16              // queries per block
#define SLC 8               // candidate slices per query
#define NT 4                // candidate tiles
#define TPTS 1024           // points per tile
#define QPT (TPTS / SLC)    // 128 candidates per (tile, slice)
#define TSTR 129            // slice stride in float4 (bank stagger: 129*16B -> +4 banks/slice)
#define MST (SLC * TOPK + 1)  // 81: merge row stride

#define FINF 3.0e38f
#define PI_F 3.14159274101257324f

__global__ __launch_bounds__(128, 4)
void repsurf_knn(const float* __restrict__ x,
                 const float* __restrict__ cw1,
                 const float* __restrict__ bg1, const float* __restrict__ bb1,
                 const float* __restrict__ bm1, const float* __restrict__ bv1,
                 const float* __restrict__ cw2, const float* __restrict__ cb2,
                 const float* __restrict__ bg2, const float* __restrict__ bb2,
                 const float* __restrict__ bm2, const float* __restrict__ bv2,
                 const float* __restrict__ cw3, const float* __restrict__ cb3,
                 float* __restrict__ out)
{
    __shared__ __align__(16) float4 tile[SLC * TSTR];  // 16.5 KB; overlaid by merge lists at end
    __shared__ float thrLds[128];
    __shared__ __align__(16) float sW1[9 * 12];
    __shared__ __align__(16) float sW2[9 * 12];
    __shared__ __align__(16) float sW3[9 * 12];
    __shared__ float sSh1[9], sSh2[9], sSh3[9];

    const int t  = threadIdx.x;
    const int b  = blockIdx.x >> 8;          // 256 chunks per batch
    const int qc = blockIdx.x & 255;
    const float* xb = x + (size_t)b * 3 * NP;

    // ---- fold BN into conv weights ----
    if (t < 108) {
        int o = t / 12, c = t % 12;
        float w1v = 0.f, w2v = 0.f, w3v = 0.f;
        if (c < 9) {
            float iv1 = bg1[o] * rsqrtf(bv1[o] + 1e-5f);
            float iv2 = bg2[o] * rsqrtf(bv2[o] + 1e-5f);
            w1v = cw1[o * 9 + c] * iv1;
            w2v = cw2[o * 9 + c] * iv2;
            w3v = cw3[o * 9 + c];
        }
        sW1[t] = w1v; sW2[t] = w2v; sW3[t] = w3v;
        if (t < 9) {
            float iv1 = bg1[t] * rsqrtf(bv1[t] + 1e-5f);
            float iv2 = bg2[t] * rsqrtf(bv2[t] + 1e-5f);
            sSh1[t] = bb1[t] - bm1[t] * iv1;
            sSh2[t] = cb2[t] * iv2 + bb2[t] - bm2[t] * iv2;
            sSh3[t] = cb3[t];
        }
    }

    const int q  = t & (QPB - 1);
    const int s  = t >> 4;                   // slice 0..7
    const int qi = qc * QPB + q;
    const float qx = xb[qi], qy = xb[NP + qi], qz = xb[2 * NP + qi];

// distance — identical expression in both phases (bit-exact match required)
#define DIST(P) fmaf((P).x - qx, (P).x - qx, fmaf((P).y - qy, (P).y - qy, ((P).z - qz) * ((P).z - qz)))

// branchless distance-only sorted insert (19 fmin/fmax, full ILP)
#define CH1(P) do { \
        float _d = DIST(P); \
        _Pragma("unroll") \
        for (int jj = TOPK - 1; jj > 0; --jj) \
            dk[jj] = fminf(dk[jj], fmaxf(dk[jj - 1], _d)); \
        dk[0] = fminf(dk[0], _d); } while (0)

    float dk[TOPK];
#pragma unroll
    for (int j = 0; j < TOPK; ++j) dk[j] = FINF;

    // ---- phase 1: branchless top-10 distances per (query, slice) ----
    for (int tt = 0; tt < NT; ++tt) {
        __syncthreads();
        for (int i = t; i < TPTS; i += 128) {
            int ss = i >> 7, m = i & 127;
            int c = tt * TPTS + i;
            tile[ss * TSTR + m] = make_float4(xb[c], xb[NP + c], xb[2 * NP + c], 0.f);
        }
        __syncthreads();
        const float4* ts = tile + s * TSTR;
        for (int g = 0; g < QPT / 4; ++g) {
            float4 P0 = ts[g * 4 + 0];
            float4 P1 = ts[g * 4 + 1];
            float4 P2 = ts[g * 4 + 2];
            float4 P3 = ts[g * 4 + 3];
            CH1(P0); CH1(P1); CH1(P2); CH1(P3);
        }
    }

    // ---- threshold: T = min over slices of each slice's 10th distance ----
    // T >= true 10th of the union; #{slice d <= T} <= 10 per slice (no overflow possible)
    thrLds[t] = dk[TOPK - 1];
    __syncthreads();
    float T = thrLds[q];
#pragma unroll
    for (int ss = 1; ss < SLC; ++ss) T = fminf(T, thrLds[ss * QPB + q]);

    float sk[TOPK];
    int   si[TOPK];
#pragma unroll
    for (int j = 0; j < TOPK; ++j) { sk[j] = FINF; si[j] = 0x7fffffff; }

#define INSERTP(DD, II) do { \
        float _d = (DD); int _i = (II); \
        if (_d < sk[TOPK - 1]) { \
            sk[TOPK - 1] = _d; si[TOPK - 1] = _i; \
            _Pragma("unroll") \
            for (int jj = TOPK - 1; jj > 0; --jj) { \
                if (sk[jj] < sk[jj - 1]) { \
                    float td = sk[jj]; sk[jj] = sk[jj - 1]; sk[jj - 1] = td; \
                    int ti = si[jj]; si[jj] = si[jj - 1]; si[jj - 1] = ti; } \
            } \
        } } while (0)

#define CH2(P, IDX) do { \
        float _dd = DIST(P); \
        if (_dd <= T) INSERTP(_dd, (IDX)); } while (0)

    // ---- phase 2: filtered rescan collecting (d, idx); inserts are rare ----
    for (int tt = 0; tt < NT; ++tt) {
        __syncthreads();
        for (int i = t; i < TPTS; i += 128) {
            int ss = i >> 7, m = i & 127;
            int c = tt * TPTS + i;
            tile[ss * TSTR + m] = make_float4(xb[c], xb[NP + c], xb[2 * NP + c], 0.f);
        }
        __syncthreads();
        const float4* ts = tile + s * TSTR;
        const int cb = tt * TPTS + s * QPT;
        for (int g = 0; g < QPT / 4; ++g) {
            float4 P0 = ts[g * 4 + 0];
            float4 P1 = ts[g * 4 + 1];
            float4 P2 = ts[g * 4 + 2];
            float4 P3 = ts[g * 4 + 3];
            CH2(P0, cb + g * 4 + 0);
            CH2(P1, cb + g * 4 + 1);
            CH2(P2, cb + g * 4 + 2);
            CH2(P3, cb + g * 4 + 3);
        }
    }
    __syncthreads();   // all tile reads done; safe to overlay merge lists

    float* md = (float*)tile;                        // [QPB][MST]
    int*   mi = (int*)((float*)tile + QPB * MST);
    const int mb = q * MST + s * TOPK;
#pragma unroll
    for (int j = 0; j < TOPK; ++j) {
        md[mb + j] = sk[j];
        mi[mb + j] = si[j];
    }
    __syncthreads();

    // ---- phase 3: 8-way merge + geometry + MLP (16 lanes) ----
    if (t < QPB) {
        const int qb = t * MST;
        int ni[KNB];
        int p0 = 0, p1 = 0, p2 = 0, p3 = 0, p4 = 0, p5 = 0, p6 = 0, p7 = 0;
#pragma unroll
        for (int j = 0; j < TOPK; ++j) {
#define GETH(K) float d##K; int i##K; \
            { int pk = p##K; \
              if (pk < TOPK) { d##K = md[qb + K * TOPK + pk]; i##K = mi[qb + K * TOPK + pk]; } \
              else { d##K = FINF; i##K = 0x7fffffff; } }
            GETH(0) GETH(1) GETH(2) GETH(3) GETH(4) GETH(5) GETH(6) GETH(7)
#undef GETH
#define WIN(DA, IA, SA, DB, IB, SB, DO_, IO_, SO_) \
            bool w_##SO_ = ((DA) < (DB)) || ((DA) == (DB) && (IA) < (IB)); \
            float DO_ = w_##SO_ ? (DA) : (DB); \
            int IO_ = w_##SO_ ? (IA) : (IB); \
            int SO_ = w_##SO_ ? (SA) : (SB);
            WIN(d0, i0, 0, d1, i1, 1, dA, iA, sA)
            WIN(d2, i2, 2, d3, i3, 3, dB, iB, sB)
            WIN(d4, i4, 4, d5, i5, 5, dC, iC, sC)
            WIN(d6, i6, 6, d7, i7, 7, dD, iD, sD)
            WIN(dA, iA, sA, dB, iB, sB, dE, iE, sE)
            WIN(dC, iC, sC, dD, iD, sD, dF, iF, sF)
            WIN(dE, iE, sE, dF, iF, sF, dG, iG, sw)
            (void)dG; (void)iG;
#undef WIN
            if (j > 0) ni[j - 1] = iG;      // drop entry 0 == self (d = 0)
            p0 += (sw == 0); p1 += (sw == 1); p2 += (sw == 2); p3 += (sw == 3);
            p4 += (sw == 4); p5 += (sw == 5); p6 += (sw == 6); p7 += (sw == 7);
        }

        float gx[KNB], gy[KNB], gz[KNB], kk[KNB];
#pragma unroll
        for (int j = 0; j < KNB; ++j) {
            int id = ni[j];
            gx[j] = xb[id] - qx;
            gy[j] = xb[NP + id] - qy;
            gz[j] = xb[2 * NP + id] - qz;
            kk[j] = atan2f(gy[j], gx[j]);
        }
#pragma unroll
        for (int pass = 0; pass < KNB - 1; ++pass) {
#pragma unroll
            for (int j = 0; j < KNB - 1 - pass; ++j) {
                if (kk[j + 1] < kk[j]) {
                    float tv;
                    tv = kk[j]; kk[j] = kk[j + 1]; kk[j + 1] = tv;
                    tv = gx[j]; gx[j] = gx[j + 1]; gx[j + 1] = tv;
                    tv = gy[j]; gy[j] = gy[j + 1]; gy[j + 1] = tv;
                    tv = gz[j]; gz[j] = gz[j + 1]; gz[j + 1] = tv;
                }
            }
        }

        float ux[KNB], uy[KNB], uz[KNB];
#pragma unroll
        for (int j = 0; j < KNB; ++j) {
            int j2 = (j + 1 == KNB) ? 0 : j + 1;
            float nx_ = gy[j] * gz[j2] - gz[j] * gy[j2];
            float ny_ = gz[j] * gx[j2] - gx[j] * gz[j2];
            float nz_ = gx[j] * gy[j2] - gy[j] * gx[j2];
            float ln = sqrtf(nx_ * nx_ + ny_ * ny_ + nz_ * nz_);
            float inv = 1.0f / fmaxf(ln, 1e-10f);
            ux[j] = nx_ * inv; uy[j] = ny_ * inv; uz[j] = nz_ * inv;
        }
        float sgn = (ux[0] > 0.0f) ? 1.0f : -1.0f;

        const float4* W1v = (const float4*)sW1;
        const float4* W2v = (const float4*)sW2;
        const float4* W3v = (const float4*)sW3;

#define DOT9(WV, O, V) ( \
        (WV)[(O)*3+0].x * (V)[0] + (WV)[(O)*3+0].y * (V)[1] + \
        (WV)[(O)*3+0].z * (V)[2] + (WV)[(O)*3+0].w * (V)[3] + \
        (WV)[(O)*3+1].x * (V)[4] + (WV)[(O)*3+1].y * (V)[5] + \
        (WV)[(O)*3+1].z * (V)[6] + (WV)[(O)*3+1].w * (V)[7] + \
        (WV)[(O)*3+2].x * (V)[8] )

        float acc[9];
#pragma unroll
        for (int o = 0; o < 9; ++o) acc[o] = 0.0f;

#pragma unroll
        for (int j = 0; j < KNB; ++j) {
            int j2 = (j + 1 == KNB) ? 0 : j + 1;
            float cx = (gx[j] + gx[j2]) * (1.0f / 3.0f);
            float cy = (gy[j] + gy[j2]) * (1.0f / 3.0f);
            float cz = (gz[j] + gz[j2]) * (1.0f / 3.0f);
            float rho = sqrtf(cx * cx + cy * cy + cz * cz);
            float rs  = fmaxf(rho, 1e-8f);
            float ct  = fminf(fmaxf(cz / rs, -1.0f), 1.0f);
            float th  = acosf(ct) / PI_F;
            float ph  = atan2f(cy, cx) / (2.0f * PI_F) + 0.5f;
            float f[9]  = {cx, cy, cz, rho, th, ph, ux[j] * sgn, uy[j] * sgn, uz[j] * sgn};
            float t1[9], t2[9];
#pragma unroll
            for (int o = 0; o < 9; ++o)
                t1[o] = fmaxf(DOT9(W1v, o, f) + sSh1[o], 0.0f);
#pragma unroll
            for (int o = 0; o < 9; ++o)
                t2[o] = fmaxf(DOT9(W2v, o, t1) + sSh2[o], 0.0f);
#pragma unroll
            for (int o = 0; o < 9; ++o)
                acc[o] += DOT9(W3v, o, t2);
        }

        float* ob = out + (size_t)b * 9 * NP;
#pragma unroll
        for (int o = 0; o < 9; ++o)
            ob[o * NP + qi] = acc[o] + 9.0f * sSh3[o];
    }
}

extern "C" void kernel_launch(void* const* d_in, const int* in_sizes, int n_in,
                              void* d_out, int out_size, void* d_ws, size_t ws_size,
                              hipStream_t stream) {
    const float* x   = (const float*)d_in[0];
    const float* cw1 = (const float*)d_in[1];
    const float* bg1 = (const float*)d_in[2];
    const float* bb1 = (const float*)d_in[3];
    const float* bm1 = (const float*)d_in[4];
    const float* bv1 = (const float*)d_in[5];
    const float* cw2 = (const float*)d_in[6];
    const float* cb2 = (const float*)d_in[7];
    const float* bg2 = (const float*)d_in[8];
    const float* bb2 = (const float*)d_in[9];
    const float* bm2 = (const float*)d_in[10];
    const float* bv2 = (const float*)d_in[11];
    const float* cw3 = (const float*)d_in[12];
    const float* cb3 = (const float*)d_in[13];
    float* out = (float*)d_out;

    hipLaunchKernelGGL(repsurf_knn, dim3(NB * (NP / QPB)), dim3(128), 0, stream,
                       x, cw1, bg1, bb1, bm1, bv1, cw2, cb2, bg2, bb2, bm2, bv2,
                       cw3, cb3, out);
}

// Round 5
// 327.274 us; speedup vs baseline: 1.4412x; 1.0677x over previous
//
#include <hip/hip_runtime.h>
#include <math.h>

#define NB 8
#define NP 4096
#define TOPK 10
#define KNB 9
#define QPB 16              // queries per block
#define SLC 8               // candidate slices per query
#define NT 8                // candidate tiles
#define TPTS 512            // points per tile
#define QPT (TPTS / SLC)    // 64 candidates per (tile, slice)
#define TSTR 65             // slice stride in float4 (64 + 1 pad -> +4 banks/slice)

#define FINF 3.0e38f
#define IINF 0x7fffffff
#define PI_F 3.14159274101257324f

__global__ __launch_bounds__(128, 3)
void repsurf_knn(const float* __restrict__ x,
                 const float* __restrict__ cw1,
                 const float* __restrict__ bg1, const float* __restrict__ bb1,
                 const float* __restrict__ bm1, const float* __restrict__ bv1,
                 const float* __restrict__ cw2, const float* __restrict__ cb2,
                 const float* __restrict__ bg2, const float* __restrict__ bb2,
                 const float* __restrict__ bm2, const float* __restrict__ bv2,
                 const float* __restrict__ cw3, const float* __restrict__ cb3,
                 float* __restrict__ out)
{
    __shared__ __align__(16) float4 tile[SLC * TSTR];      // 8320 B
    __shared__ float svD[QPB * SLC * TOPK];                // 5120 B: per-(q,s) sorted dist runs
    __shared__ int   svI[QPB * SLC * TOPK];                // 5120 B: matching indices (prefix)
    __shared__ float Tst[QPB];                             // exact union 10th per query
    __shared__ __align__(16) float sW1[9 * 12];
    __shared__ __align__(16) float sW2[9 * 12];
    __shared__ __align__(16) float sW3[9 * 12];
    __shared__ float sSh1[9], sSh2[9], sSh3[9];

    const int t  = threadIdx.x;
    const int b  = blockIdx.x >> 8;          // 256 chunks per batch
    const int qc = blockIdx.x & 255;
    const float* xb = x + (size_t)b * 3 * NP;

    // ---- fold BN into conv weights ----
    if (t < 108) {
        int o = t / 12, c = t % 12;
        float w1v = 0.f, w2v = 0.f, w3v = 0.f;
        if (c < 9) {
            float iv1 = bg1[o] * rsqrtf(bv1[o] + 1e-5f);
            float iv2 = bg2[o] * rsqrtf(bv2[o] + 1e-5f);
            w1v = cw1[o * 9 + c] * iv1;
            w2v = cw2[o * 9 + c] * iv2;
            w3v = cw3[o * 9 + c];
        }
        sW1[t] = w1v; sW2[t] = w2v; sW3[t] = w3v;
        if (t < 9) {
            float iv1 = bg1[t] * rsqrtf(bv1[t] + 1e-5f);
            float iv2 = bg2[t] * rsqrtf(bv2[t] + 1e-5f);
            sSh1[t] = bb1[t] - bm1[t] * iv1;
            sSh2[t] = cb2[t] * iv2 + bb2[t] - bm2[t] * iv2;
            sSh3[t] = cb3[t];
        }
    }

    const int q  = t & (QPB - 1);
    const int s  = t >> 4;                   // slice 0..7
    const int qi = qc * QPB + q;
    const float qx = xb[qi], qy = xb[NP + qi], qz = xb[2 * NP + qi];

// identical expression in both phases (bit-exact match required)
#define DIST(P) fmaf((P).x - qx, (P).x - qx, fmaf((P).y - qy, (P).y - qy, ((P).z - qz) * ((P).z - qz)))

// branchless distance-only sorted insert (19 fmin/fmax, full ILP)
#define CH1(P) do { \
        float _d = DIST(P); \
        _Pragma("unroll") \
        for (int jj = TOPK - 1; jj > 0; --jj) \
            dk[jj] = fminf(dk[jj], fmaxf(dk[jj - 1], _d)); \
        dk[0] = fminf(dk[0], _d); } while (0)

    float dk[TOPK];
#pragma unroll
    for (int j = 0; j < TOPK; ++j) dk[j] = FINF;

    // ---- phase 1: branchless top-10 distances per (query, slice) ----
    for (int tt = 0; tt < NT; ++tt) {
        __syncthreads();
#pragma unroll
        for (int i = t; i < TPTS; i += 128) {
            int ss = i >> 6, m = i & 63;
            int c = tt * TPTS + i;
            tile[ss * TSTR + m] = make_float4(xb[c], xb[NP + c], xb[2 * NP + c], 0.f);
        }
        __syncthreads();
        const float4* ts = tile + s * TSTR;
#pragma unroll 4
        for (int g = 0; g < QPT / 4; ++g) {
            float4 P0 = ts[g * 4 + 0];
            float4 P1 = ts[g * 4 + 1];
            float4 P2 = ts[g * 4 + 2];
            float4 P3 = ts[g * 4 + 3];
            CH1(P0); CH1(P1); CH1(P2); CH1(P3);
        }
    }

    // ---- write sorted distance runs; compute exact union 10th T* ----
    const int rb = (q * SLC + s) * TOPK;
#pragma unroll
    for (int j = 0; j < TOPK; ++j) svD[rb + j] = dk[j];
    __syncthreads();

    if (t < QPB) {
        // value-only 8-way merge, 10 picks; heads never exceed index 9 (<=10 picks total)
        int p0 = 0, p1 = 0, p2 = 0, p3 = 0, p4 = 0, p5 = 0, p6 = 0, p7 = 0;
        const int mbq = t * SLC * TOPK;
        float last = 0.f;
#pragma unroll
        for (int j = 0; j < TOPK; ++j) {
            float v0 = svD[mbq + 0 * TOPK + p0];
            float v1 = svD[mbq + 1 * TOPK + p1];
            float v2 = svD[mbq + 2 * TOPK + p2];
            float v3 = svD[mbq + 3 * TOPK + p3];
            float v4 = svD[mbq + 4 * TOPK + p4];
            float v5 = svD[mbq + 5 * TOPK + p5];
            float v6 = svD[mbq + 6 * TOPK + p6];
            float v7 = svD[mbq + 7 * TOPK + p7];
            float m01 = fminf(v0, v1), m23 = fminf(v2, v3);
            float m45 = fminf(v4, v5), m67 = fminf(v6, v7);
            float m03 = fminf(m01, m23), m47 = fminf(m45, m67);
            float mv  = fminf(m03, m47);
            last = mv;
            // advance exactly one head holding mv (lowest slice index on ties)
            bool a0 = (v0 == mv);
            bool a1 = (v1 == mv) && !a0;
            bool a2 = (v2 == mv) && !(a0 | a1);
            bool a3 = (v3 == mv) && !(a0 | a1 | a2);
            bool a4 = (v4 == mv) && !(a0 | a1 | a2 | a3);
            bool a5 = (v5 == mv) && !(a0 | a1 | a2 | a3 | a4);
            bool a6 = (v6 == mv) && !(a0 | a1 | a2 | a3 | a4 | a5);
            bool a7 = (v7 == mv) && !(a0 | a1 | a2 | a3 | a4 | a5 | a6);
            p0 += a0; p1 += a1; p2 += a2; p3 += a3;
            p4 += a4; p5 += a5; p6 += a6; p7 += a7;
        }
        Tst[t] = last;
    }
    // init survivor indices (svI untouched so far)
#pragma unroll
    for (int i = t; i < QPB * SLC * TOPK; i += 128) svI[i] = IINF;
    __syncthreads();

    const float Tq = Tst[q];

// phase-2 body: survivor's rank within this lane's sorted dk = its slot; write index only
#define CH2(P, IDX) do { \
        float _d = DIST(P); \
        if (_d <= Tq) { \
            int rk = 0; \
            _Pragma("unroll") \
            for (int jj = 0; jj < TOPK - 1; ++jj) rk += (dk[jj] < _d); \
            while (rk < TOPK - 1 && svI[rb + rk] != IINF) ++rk;  /* exact-tie advance */ \
            if (svI[rb + rk] == IINF) svI[rb + rk] = (IDX); \
        } } while (0)

    // ---- phase 2: filtered rescan writing indices ----
    for (int tt = 0; tt < NT; ++tt) {
        __syncthreads();
#pragma unroll
        for (int i = t; i < TPTS; i += 128) {
            int ss = i >> 6, m = i & 63;
            int c = tt * TPTS + i;
            tile[ss * TSTR + m] = make_float4(xb[c], xb[NP + c], xb[2 * NP + c], 0.f);
        }
        __syncthreads();
        const float4* ts = tile + s * TSTR;
        const int cb = tt * TPTS + s * QPT;
#pragma unroll 4
        for (int g = 0; g < QPT / 4; ++g) {
            float4 P0 = ts[g * 4 + 0];
            float4 P1 = ts[g * 4 + 1];
            float4 P2 = ts[g * 4 + 2];
            float4 P3 = ts[g * 4 + 3];
            CH2(P0, cb + g * 4 + 0);
            CH2(P1, cb + g * 4 + 1);
            CH2(P2, cb + g * 4 + 2);
            CH2(P3, cb + g * 4 + 3);
        }
    }
    __syncthreads();

    // ---- phase 3: 8-way (d, idx) merge + geometry + MLP (16 lanes) ----
    if (t < QPB) {
        const int qb = t * SLC * TOPK;
        int ni[KNB];
        int p0 = 0, p1 = 0, p2 = 0, p3 = 0, p4 = 0, p5 = 0, p6 = 0, p7 = 0;
#pragma unroll
        for (int j = 0; j < TOPK; ++j) {
#define GETH(K) float d##K; int i##K; \
            { int pk = p##K; \
              if (pk < TOPK) { d##K = svD[qb + K * TOPK + pk]; i##K = svI[qb + K * TOPK + pk]; } \
              else { d##K = FINF; i##K = IINF; } }
            GETH(0) GETH(1) GETH(2) GETH(3) GETH(4) GETH(5) GETH(6) GETH(7)
#undef GETH
#define WIN(DA, IA, SA, DB, IB, SB, DO_, IO_, SO_) \
            bool w_##SO_ = ((DA) < (DB)) || ((DA) == (DB) && (IA) < (IB)); \
            float DO_ = w_##SO_ ? (DA) : (DB); \
            int IO_ = w_##SO_ ? (IA) : (IB); \
            int SO_ = w_##SO_ ? (SA) : (SB);
            WIN(d0, i0, 0, d1, i1, 1, dA, iA, sA)
            WIN(d2, i2, 2, d3, i3, 3, dB, iB, sB)
            WIN(d4, i4, 4, d5, i5, 5, dC, iC, sC)
            WIN(d6, i6, 6, d7, i7, 7, dD, iD, sD)
            WIN(dA, iA, sA, dB, iB, sB, dE, iE, sE)
            WIN(dC, iC, sC, dD, iD, sD, dF, iF, sF)
            WIN(dE, iE, sE, dF, iF, sF, dG, iG, sw)
            (void)dG; (void)iG;
#undef WIN
            if (j > 0) ni[j - 1] = iG;      // drop entry 0 == self (d = 0)
            p0 += (sw == 0); p1 += (sw == 1); p2 += (sw == 2); p3 += (sw == 3);
            p4 += (sw == 4); p5 += (sw == 5); p6 += (sw == 6); p7 += (sw == 7);
        }

        float gx[KNB], gy[KNB], gz[KNB], kk[KNB];
#pragma unroll
        for (int j = 0; j < KNB; ++j) {
            int id = ni[j];
            gx[j] = xb[id] - qx;
            gy[j] = xb[NP + id] - qy;
            gz[j] = xb[2 * NP + id] - qz;
            kk[j] = atan2f(gy[j], gx[j]);
        }
#pragma unroll
        for (int pass = 0; pass < KNB - 1; ++pass) {
#pragma unroll
            for (int j = 0; j < KNB - 1 - pass; ++j) {
                if (kk[j + 1] < kk[j]) {
                    float tv;
                    tv = kk[j]; kk[j] = kk[j + 1]; kk[j + 1] = tv;
                    tv = gx[j]; gx[j] = gx[j + 1]; gx[j + 1] = tv;
                    tv = gy[j]; gy[j] = gy[j + 1]; gy[j + 1] = tv;
                    tv = gz[j]; gz[j] = gz[j + 1]; gz[j + 1] = tv;
                }
            }
        }

        float ux[KNB], uy[KNB], uz[KNB];
#pragma unroll
        for (int j = 0; j < KNB; ++j) {
            int j2 = (j + 1 == KNB) ? 0 : j + 1;
            float nx_ = gy[j] * gz[j2] - gz[j] * gy[j2];
            float ny_ = gz[j] * gx[j2] - gx[j] * gz[j2];
            float nz_ = gx[j] * gy[j2] - gy[j] * gx[j2];
            float ln = sqrtf(nx_ * nx_ + ny_ * ny_ + nz_ * nz_);
            float inv = 1.0f / fmaxf(ln, 1e-10f);
            ux[j] = nx_ * inv; uy[j] = ny_ * inv; uz[j] = nz_ * inv;
        }
        float sgn = (ux[0] > 0.0f) ? 1.0f : -1.0f;

        const float4* W1v = (const float4*)sW1;
        const float4* W2v = (const float4*)sW2;
        const float4* W3v = (const float4*)sW3;

#define DOT9(WV, O, V) ( \
        (WV)[(O)*3+0].x * (V)[0] + (WV)[(O)*3+0].y * (V)[1] + \
        (WV)[(O)*3+0].z * (V)[2] + (WV)[(O)*3+0].w * (V)[3] + \
        (WV)[(O)*3+1].x * (V)[4] + (WV)[(O)*3+1].y * (V)[5] + \
        (WV)[(O)*3+1].z * (V)[6] + (WV)[(O)*3+1].w * (V)[7] + \
        (WV)[(O)*3+2].x * (V)[8] )

        float acc[9];
#pragma unroll
        for (int o = 0; o < 9; ++o) acc[o] = 0.0f;

#pragma unroll
        for (int j = 0; j < KNB; ++j) {
            int j2 = (j + 1 == KNB) ? 0 : j + 1;
            float cx = (gx[j] + gx[j2]) * (1.0f / 3.0f);
            float cy = (gy[j] + gy[j2]) * (1.0f / 3.0f);
            float cz = (gz[j] + gz[j2]) * (1.0f / 3.0f);
            float rho = sqrtf(cx * cx + cy * cy + cz * cz);
            float rs  = fmaxf(rho, 1e-8f);
            float ct  = fminf(fmaxf(cz / rs, -1.0f), 1.0f);
            float th  = acosf(ct) / PI_F;
            float ph  = atan2f(cy, cx) / (2.0f * PI_F) + 0.5f;
            float f[9]  = {cx, cy, cz, rho, th, ph, ux[j] * sgn, uy[j] * sgn, uz[j] * sgn};
            float t1[9], t2[9];
#pragma unroll
            for (int o = 0; o < 9; ++o)
                t1[o] = fmaxf(DOT9(W1v, o, f) + sSh1[o], 0.0f);
#pragma unroll
            for (int o = 0; o < 9; ++o)
                t2[o] = fmaxf(DOT9(W2v, o, t1) + sSh2[o], 0.0f);
#pragma unroll
            for (int o = 0; o < 9; ++o)
                acc[o] += DOT9(W3v, o, t2);
        }

        float* ob = out + (size_t)b * 9 * NP;
#pragma unroll
        for (int o = 0; o < 9; ++o)
            ob[o * NP + qi] = acc[o] + 9.0f * sSh3[o];
    }
}

extern "C" void kernel_launch(void* const* d_in, const int* in_sizes, int n_in,
                              void* d_out, int out_size, void* d_ws, size_t ws_size,
                              hipStream_t stream) {
    const float* x   = (const float*)d_in[0];
    const float* cw1 = (const float*)d_in[1];
    const float* bg1 = (const float*)d_in[2];
    const float* bb1 = (const float*)d_in[3];
    const float* bm1 = (const float*)d_in[4];
    const float* bv1 = (const float*)d_in[5];
    const float* cw2 = (const float*)d_in[6];
    const float* cb2 = (const float*)d_in[7];
    const float* bg2 = (const float*)d_in[8];
    const float* bb2 = (const float*)d_in[9];
    const float* bm2 = (const float*)d_in[10];
    const float* bv2 = (const float*)d_in[11];
    const float* cw3 = (const float*)d_in[12];
    const float* cb3 = (const float*)d_in[13];
    float* out = (float*)d_out;

    hipLaunchKernelGGL(repsurf_knn, dim3(NB * (NP / QPB)), dim3(128), 0, stream,
                       x, cw1, bg1, bb1, bm1, bv1, cw2, cb2, bg2, bb2, bm2, bv2,
                       cw3, cb3, out);
}